// Round 4
// baseline (545.664 us; speedup 1.0000x reference)
//
#include <hip/hip_runtime.h>
#include <hip/hip_bf16.h>
#include <stdint.h>

typedef unsigned short bf16_t;
typedef __attribute__((ext_vector_type(4))) short s4v;
typedef __attribute__((ext_vector_type(8))) short short8;
typedef __attribute__((ext_vector_type(4))) float f32x4;

__device__ __forceinline__ bf16_t f2b(float f) {
    union { float f; uint32_t u; } v; v.f = f;
    uint32_t u = v.u;
    return (bf16_t)((u + 0x7FFFu + ((u >> 16) & 1u)) >> 16);
}

__global__ __launch_bounds__(256) void cvt_f32_bf16(const float* __restrict__ in,
                                                    bf16_t* __restrict__ out, int n4) {
    int i = blockIdx.x * blockDim.x + threadIdx.x;
    if (i >= n4) return;
    float4 f = ((const float4*)in)[i];
    ushort4 o;
    o.x = f2b(f.x); o.y = f2b(f.y); o.z = f2b(f.z); o.w = f2b(f.w);
    ((ushort4*)out)[i] = o;
}

// three 512x512 weight matrices in one launch
__global__ __launch_bounds__(256) void cvt_w3(const float* __restrict__ a,
                                              const float* __restrict__ b,
                                              const float* __restrict__ c,
                                              bf16_t* __restrict__ out) {
    int i = blockIdx.x * blockDim.x + threadIdx.x;   // 0..196607
    const int which = i >> 16;
    const int idx   = i & 65535;
    const float* src = (which == 0) ? a : (which == 1) ? b : c;
    float4 f = ((const float4*)src)[idx];
    ushort4 o;
    o.x = f2b(f.x); o.y = f2b(f.y); o.z = f2b(f.z); o.w = f2b(f.w);
    ((ushort4*)out)[i] = o;
}

__device__ __forceinline__ void lds_dma16(const void* g, void* l) {
    __builtin_amdgcn_global_load_lds(
        (const __attribute__((address_space(1))) void*)g,
        (__attribute__((address_space(3))) void*)l, 16, 0, 0);
}

// BK=64 swizzle contract: LDS[row][ch] holds global chunk (ch ^ (row&7));
// reader wanting global chunk g of row r reads LDS[r][g ^ (r&7)].
// Epilogue bounce contract (64x64 bf16 per wave, 8KB):
//   row-major: wbuf[row*64 + (col ^ ((row&7)<<3))]  -> read short8 at
//              wbuf[row*64 + (c0 ^ ((row&7)<<3))] gives cols c0..c0+7.

// ---------- projections: Q/K/V fused, flat grid (1536 blocks) ----------
__global__ __launch_bounds__(256)
void proj_all(const bf16_t* __restrict__ Xb, const bf16_t* __restrict__ Wb,
              const float* __restrict__ qb, const float* __restrict__ kb,
              const float* __restrict__ vb,
              bf16_t* __restrict__ Qb, bf16_t* __restrict__ Kb,
              bf16_t* __restrict__ Vt)
{
    __shared__ __align__(16) bf16_t lds[16384];   // 32 KB: staging, then bounce
    bf16_t* lsA = lds;
    bf16_t* lsB = lds + 8192;

    const int tid  = threadIdx.x;
    const int lane = tid & 63;
    const int w    = tid >> 6;
    const int wm   = w & 1, wn = w >> 1;
    const int ll   = lane & 15;
    const int quad = lane >> 4;

    // xcd x owns m-panels [16x..16x+15]; inner = 4n x 3z per panel.
    const int bid   = blockIdx.x;
    const int x     = bid & 7;
    const int g     = bid >> 3;        // 0..191
    const int mi    = x * 16 + g / 12; // 0..127
    const int inner = g % 12;
    const int m0 = mi * 128;
    const int n0 = (inner & 3) * 128;
    const int z  = inner >> 2;         // 0..2

    const bf16_t* A = Xb;
    const bf16_t* B = Wb + z * 262144;

    f32x4 acc[4][4];
#pragma unroll
    for (int i = 0; i < 4; i++)
#pragma unroll
        for (int j = 0; j < 4; j++) acc[i][j] = (f32x4){0.f, 0.f, 0.f, 0.f};

    for (int k0 = 0; k0 < 512; k0 += 64) {
#pragma unroll
        for (int c = 0; c < 4; ++c) {
            const int base = (c * 4 + w) * 64;
            const int slot = base + lane;
            const int row  = slot >> 3;
            const int kc   = ((slot & 7) ^ (row & 7)) << 3;
            lds_dma16(A + (size_t)(m0 + row) * 512 + k0 + kc, (char*)lsA + base * 16);
            lds_dma16(B + (size_t)(n0 + row) * 512 + k0 + kc, (char*)lsB + base * 16);
        }
        __syncthreads();

#pragma unroll
        for (int t = 0; t < 2; t++) {
            short8 af[4], bf[4];
#pragma unroll
            for (int i = 0; i < 4; i++) {
                const int ri = wm * 64 + i * 16 + ll;
                const int rj = wn * 64 + i * 16 + ll;
                af[i] = *(const short8*)(lsA + ri * 64 + (((t * 4 + quad) ^ (ll & 7)) << 3));
                bf[i] = *(const short8*)(lsB + rj * 64 + (((t * 4 + quad) ^ (ll & 7)) << 3));
            }
#pragma unroll
            for (int i = 0; i < 4; i++)
#pragma unroll
                for (int j = 0; j < 4; j++)
                    acc[i][j] = __builtin_amdgcn_mfma_f32_16x16x32_bf16(af[i], bf[j], acc[i][j], 0, 0, 0);
        }
        __syncthreads();
    }

    // ---- epilogue: bounce through LDS for coalesced 16B stores ----
    bf16_t* wbuf = lds + w * 4096;     // 64x64 bf16 per wave
    const float inv = 0.044194173824159216f;  // 1/sqrt(512)

    if (z != 2) {
        const float* bptr = (z == 0) ? qb : kb;
        const float scl   = (z == 0) ? inv : 1.0f;
#pragma unroll
        for (int j = 0; j < 4; j++) {
            const int colL = j * 16 + ll;
            const float bv = bptr[n0 + wn * 64 + colL];
#pragma unroll
            for (int i = 0; i < 4; i++) {
                f32x4 a = acc[i][j];
#pragma unroll
                for (int r = 0; r < 4; r++) {
                    const int rowL = i * 16 + quad * 4 + r;
                    wbuf[rowL * 64 + (colL ^ ((rowL & 7) << 3))] = f2b((a[r] + bv) * scl);
                }
            }
        }
        __syncthreads();
        bf16_t* dst = (z == 0) ? Qb : Kb;
        const int rowg0 = m0 + wm * 64;
        const int colg0 = n0 + wn * 64;
#pragma unroll
        for (int k = 0; k < 8; k++) {
            const int rowL = (lane >> 3) + k * 8;
            const int c0   = (lane & 7) * 8;
            short8 vv = *(const short8*)(wbuf + rowL * 64 + (c0 ^ ((rowL & 7) << 3)));
            *(short8*)(dst + (size_t)(rowg0 + rowL) * 512 + colg0 + c0) = vv;
        }
    } else {
        // V: store transposed Vt[b][d][s]; bounce col-major (d-major)
#pragma unroll
        for (int j = 0; j < 4; j++) {
            const int d = j * 16 + ll;
            const float bv = vb[n0 + wn * 64 + d];
#pragma unroll
            for (int i = 0; i < 4; i++) {
                f32x4 a = acc[i][j];
                s4v pk;
                pk[0] = (short)f2b(a[0] + bv);
                pk[1] = (short)f2b(a[1] + bv);
                pk[2] = (short)f2b(a[2] + bv);
                pk[3] = (short)f2b(a[3] + bv);
                const int sB = i * 16 + quad * 4;
                *(s4v*)(wbuf + d * 64 + (sB ^ ((d & 7) << 3))) = pk;
            }
        }
        __syncthreads();
        const int rowg0 = m0 + wm * 64;
        const int b  = rowg0 >> 12;
        const int s0 = rowg0 & 4095;
        const int d0 = n0 + wn * 64;
#pragma unroll
        for (int k = 0; k < 8; k++) {
            const int dL = (lane >> 3) + k * 8;
            const int c0 = (lane & 7) * 8;
            short8 vv = *(const short8*)(wbuf + dL * 64 + (c0 ^ ((dL & 7) << 3)));
            *(short8*)(Vt + ((size_t)b * 512 + d0 + dL) * 4096 + s0 + c0) = vv;
        }
    }
}

// ---------- scores: P = sigmoid(Q K^T + bias), z-loop inside block ----------
// grid = 1024 blocks (one per (m,n) tile, supertile order); each block computes
// all 4 batches for its tile -> 64 KB bias tile read once from EA, L1/L2-hit
// for z=1..3.  #pragma unroll 1 keeps one z's state live (round-3 lesson:
// compiler unrolled z-loop -> 184 VGPR -> 11% occupancy).  launch_bounds(256,4)
// = 4 blocks/CU target, VGPR cap 128.
__global__ __launch_bounds__(256, 4)
void scores_sig(const bf16_t* __restrict__ Qb, const bf16_t* __restrict__ Kb,
                const float* __restrict__ bias, bf16_t* __restrict__ P)
{
    __shared__ __align__(16) bf16_t lds[16384];
    bf16_t* lsA = lds;
    bf16_t* lsB = lds + 8192;

    const int tid  = threadIdx.x;
    const int lane = tid & 63;
    const int w    = tid >> 6;
    const int wm   = w & 1, wn = w >> 1;
    const int ll   = lane & 15;
    const int quad = lane >> 4;

    const int t_  = blockIdx.x;           // 0..1023
    const int sup = t_ >> 5;              // 32 supertiles (8 in m x 4 in n)
    const int win = t_ & 31;              // 32 tiles per supertile (4m x 8n)
    const int m0  = ((sup >> 2) * 4 + (win & 3)) * 128;
    const int n0  = ((sup & 3) * 8 + (win >> 2)) * 128;

    const int rowg0 = m0 + wm * 64;
    const int colg0 = n0 + wn * 64;
    bf16_t* wbuf = lds + w * 4096;

#pragma unroll 1
    for (int z = 0; z < 4; ++z) {
        const bf16_t* A = Qb + (size_t)z * 2097152;
        const bf16_t* B = Kb + (size_t)z * 2097152;
        bf16_t* out = P + (size_t)z * 16777216;

        f32x4 acc[4][4];
#pragma unroll
        for (int i = 0; i < 4; i++)
#pragma unroll
            for (int j = 0; j < 4; j++) acc[i][j] = (f32x4){0.f, 0.f, 0.f, 0.f};

        __syncthreads();   // protect LDS (staging aliases wbuf) across z iters

#pragma unroll 1
        for (int k0 = 0; k0 < 512; k0 += 64) {
#pragma unroll
            for (int c = 0; c < 4; ++c) {
                const int base = (c * 4 + w) * 64;
                const int slot = base + lane;
                const int row  = slot >> 3;
                const int kc   = ((slot & 7) ^ (row & 7)) << 3;
                lds_dma16(A + (size_t)(m0 + row) * 512 + k0 + kc, (char*)lsA + base * 16);
                lds_dma16(B + (size_t)(n0 + row) * 512 + k0 + kc, (char*)lsB + base * 16);
            }
            __syncthreads();

#pragma unroll
            for (int t = 0; t < 2; t++) {
                short8 af[4], bf[4];
#pragma unroll
                for (int i = 0; i < 4; i++) {
                    const int ri = wm * 64 + i * 16 + ll;
                    const int rj = wn * 64 + i * 16 + ll;
                    af[i] = *(const short8*)(lsA + ri * 64 + (((t * 4 + quad) ^ (ll & 7)) << 3));
                    bf[i] = *(const short8*)(lsB + rj * 64 + (((t * 4 + quad) ^ (ll & 7)) << 3));
                }
#pragma unroll
                for (int i = 0; i < 4; i++)
#pragma unroll
                    for (int j = 0; j < 4; j++)
                        acc[i][j] = __builtin_amdgcn_mfma_f32_16x16x32_bf16(af[i], bf[j], acc[i][j], 0, 0, 0);
            }
            __syncthreads();
        }

        // epilogue: bias + sigmoid into per-wave LDS bounce, 16B coalesced stores
#pragma unroll
        for (int i = 0; i < 4; i++) {
#pragma unroll
            for (int j = 0; j < 4; j++) {
                const int colL = j * 16 + ll;
                const int colg = n0 + wn * 64 + colL;
                const int rowb = m0 + wm * 64 + i * 16 + quad * 4;
                f32x4 a = acc[i][j];
#pragma unroll
                for (int r = 0; r < 4; r++) {
                    const float v = a[r] + bias[(size_t)(rowb + r) * 4096 + colg];
                    const float p = __builtin_amdgcn_rcpf(1.f + __expf(-v));
                    const int rowL = i * 16 + quad * 4 + r;
                    wbuf[rowL * 64 + (colL ^ ((rowL & 7) << 3))] = (bf16_t)(__float_as_uint(p) >> 16);
                }
            }
        }
        __syncthreads();
#pragma unroll
        for (int k = 0; k < 8; k++) {
            const int rowL = (lane >> 3) + k * 8;
            const int c0   = (lane & 7) * 8;
            short8 vv = *(const short8*)(wbuf + rowL * 64 + (c0 ^ ((rowL & 7) << 3)));
            *(short8*)(out + (size_t)(rowg0 + rowL) * 4096 + colg0 + c0) = vv;
        }
    }
}

// ---------- PV: out = P * Vt^T, BM=32 BN=256, BK=64, 1024 blocks = 4/CU ----------
// Round-2 counters showed pv drain-exposed at low co-residency (16% Mfma, 7%
// VALU, 9% HBM).  BM=32 doubles the grid to 4 blocks/CU (LDS 36 KB) so other
// blocks' MFMA covers each block's vmcnt(0)+barrier drain.
__global__ __launch_bounds__(256, 4)
void pv_gemm(const bf16_t* __restrict__ P, const bf16_t* __restrict__ Vt,
             float* __restrict__ outg)
{
    __shared__ __align__(16) bf16_t lsA[32 * 64];    // 4 KB
    __shared__ __align__(16) bf16_t lsB[256 * 64];   // 32 KB

    const int tid  = threadIdx.x;
    const int lane = tid & 63;
    const int w    = tid >> 6;
    const int wn   = w;            // 0..3: 64-col group
    const int ll   = lane & 15;
    const int quad = lane >> 4;

    const int n0 = blockIdx.x * 256;
    const int m0 = blockIdx.y * 32;
    const int z  = blockIdx.z;

    const bf16_t* A = P + (size_t)z * 16777216;   // [4096][4096]
    const bf16_t* B = Vt + (size_t)z * 2097152;   // [512][4096]
    float* out = outg + (size_t)z * 2097152;

    f32x4 acc[2][4];
#pragma unroll
    for (int i = 0; i < 2; i++)
#pragma unroll
        for (int j = 0; j < 4; j++) acc[i][j] = (f32x4){0.f, 0.f, 0.f, 0.f};

    for (int k0 = 0; k0 < 4096; k0 += 64) {
        // A: 32x8 = 256 chunks, 1 round of 256 threads
        {
            const int slot = tid;
            const int row  = slot >> 3;
            const int kc   = ((slot & 7) ^ (row & 7)) << 3;
            lds_dma16(A + (size_t)(m0 + row) * 4096 + k0 + kc, (char*)lsA + slot * 16);
        }
        // B: 256x8 = 2048 chunks, 8 rounds
#pragma unroll
        for (int c = 0; c < 8; ++c) {
            const int slot = c * 256 + tid;
            const int row  = slot >> 3;
            const int kc   = ((slot & 7) ^ (row & 7)) << 3;
            lds_dma16(B + (size_t)(n0 + row) * 4096 + k0 + kc, (char*)lsB + slot * 16);
        }
        __syncthreads();

#pragma unroll
        for (int t = 0; t < 2; t++) {
            short8 af[2], bf[4];
#pragma unroll
            for (int i = 0; i < 2; i++) {
                const int ri = i * 16 + ll;
                af[i] = *(const short8*)(lsA + ri * 64 + (((t * 4 + quad) ^ (ll & 7)) << 3));
            }
#pragma unroll
            for (int j = 0; j < 4; j++) {
                const int rj = wn * 64 + j * 16 + ll;
                bf[j] = *(const short8*)(lsB + rj * 64 + (((t * 4 + quad) ^ (ll & 7)) << 3));
            }
#pragma unroll
            for (int i = 0; i < 2; i++)
#pragma unroll
                for (int j = 0; j < 4; j++)
                    acc[i][j] = __builtin_amdgcn_mfma_f32_16x16x32_bf16(af[i], bf[j], acc[i][j], 0, 0, 0);
        }
        __syncthreads();
    }

#pragma unroll
    for (int i = 0; i < 2; i++) {
#pragma unroll
        for (int j = 0; j < 4; j++) {
            const int col  = n0 + wn * 64 + j * 16 + ll;
            const int rowb = m0 + i * 16 + quad * 4;
            f32x4 a = acc[i][j];
#pragma unroll
            for (int r = 0; r < 4; r++)
                out[(size_t)(rowb + r) * 512 + col] = a[r];
        }
    }
}

extern "C" void kernel_launch(void* const* d_in, const int* in_sizes, int n_in,
                              void* d_out, int out_size, void* d_ws, size_t ws_size,
                              hipStream_t stream) {
    (void)in_sizes; (void)n_in; (void)out_size; (void)ws_size;
    const float* x    = (const float*)d_in[0];
    const float* bias = (const float*)d_in[1];
    const float* Wq_w = (const float*)d_in[2];
    const float* Wq_b = (const float*)d_in[3];
    const float* Wk_w = (const float*)d_in[4];
    const float* Wk_b = (const float*)d_in[5];
    const float* Wv_w = (const float*)d_in[6];
    const float* Wv_b = (const float*)d_in[7];
    float* out = (float*)d_out;

    // workspace layout (bf16 elements)
    bf16_t* Xb = (bf16_t*)d_ws;                    // 16384 x 512
    bf16_t* Wb = Xb + (size_t)16384 * 512;         // 3 x 512 x 512
    bf16_t* Qb = Wb + (size_t)3 * 512 * 512;       // 16384 x 512 (pre-scaled 1/sqrt(D))
    bf16_t* Kb = Qb + (size_t)16384 * 512;         // 16384 x 512
    bf16_t* Vt = Kb + (size_t)16384 * 512;         // 4 x 512 x 4096 (transposed V)
    bf16_t* P  = Vt + (size_t)16384 * 512;         // 4 x 4096 x 4096

    cvt_f32_bf16<<<8192, 256, 0, stream>>>(x, Xb, 2097152);
    cvt_w3<<<768, 256, 0, stream>>>(Wq_w, Wk_w, Wv_w, Wb);

    // all three projections in one launch
    proj_all<<<1536, 256, 0, stream>>>(Xb, Wb, Wq_b, Wk_b, Wv_b, Qb, Kb, Vt);
    // scores + sigmoid; 1024 tiles, z-loop inside (bias L2 reuse)
    scores_sig<<<1024, 256, 0, stream>>>(Qb, Kb, bias, P);
    // out = P * V, 32x256 tiles, BK=64, 4 blocks/CU
    pv_gemm<<<dim3(2, 128, 4), 256, 0, stream>>>(P, Vt, out);
}

// Round 5
// 412.614 us; speedup vs baseline: 1.3225x; 1.3225x over previous
//
#include <hip/hip_runtime.h>
#include <hip/hip_bf16.h>
#include <stdint.h>

typedef unsigned short bf16_t;
typedef __attribute__((ext_vector_type(4))) short s4v;
typedef __attribute__((ext_vector_type(8))) short short8;
typedef __attribute__((ext_vector_type(4))) float f32x4;

__device__ __forceinline__ bf16_t f2b(float f) {
    union { float f; uint32_t u; } v; v.f = f;
    uint32_t u = v.u;
    return (bf16_t)((u + 0x7FFFu + ((u >> 16) & 1u)) >> 16);
}

__global__ __launch_bounds__(256) void cvt_f32_bf16(const float* __restrict__ in,
                                                    bf16_t* __restrict__ out, int n4) {
    int i = blockIdx.x * blockDim.x + threadIdx.x;
    if (i >= n4) return;
    float4 f = ((const float4*)in)[i];
    ushort4 o;
    o.x = f2b(f.x); o.y = f2b(f.y); o.z = f2b(f.z); o.w = f2b(f.w);
    ((ushort4*)out)[i] = o;
}

// three 512x512 weight matrices in one launch
__global__ __launch_bounds__(256) void cvt_w3(const float* __restrict__ a,
                                              const float* __restrict__ b,
                                              const float* __restrict__ c,
                                              bf16_t* __restrict__ out) {
    int i = blockIdx.x * blockDim.x + threadIdx.x;   // 0..196607
    const int which = i >> 16;
    const int idx   = i & 65535;
    const float* src = (which == 0) ? a : (which == 1) ? b : c;
    float4 f = ((const float4*)src)[idx];
    ushort4 o;
    o.x = f2b(f.x); o.y = f2b(f.y); o.z = f2b(f.z); o.w = f2b(f.w);
    ((ushort4*)out)[i] = o;
}

__device__ __forceinline__ void lds_dma16(const void* g, void* l) {
    __builtin_amdgcn_global_load_lds(
        (const __attribute__((address_space(1))) void*)g,
        (__attribute__((address_space(3))) void*)l, 16, 0, 0);
}

// BK=64 swizzle contract: LDS[row][ch] holds global chunk (ch ^ (row&7));
// reader wanting global chunk g of row r reads LDS[r][g ^ (r&7)].
// Epilogue bounce contract (64x64 bf16 per wave, 8KB):
//   row-major: wbuf[row*64 + (col ^ ((row&7)<<3))]  -> read short8 at
//              wbuf[row*64 + (c0 ^ ((row&7)<<3))] gives cols c0..c0+7.

// ---------- projections: Q/K/V fused, flat grid (1536 blocks) ----------
__global__ __launch_bounds__(256)
void proj_all(const bf16_t* __restrict__ Xb, const bf16_t* __restrict__ Wb,
              const float* __restrict__ qb, const float* __restrict__ kb,
              const float* __restrict__ vb,
              bf16_t* __restrict__ Qb, bf16_t* __restrict__ Kb,
              bf16_t* __restrict__ Vt)
{
    __shared__ __align__(16) bf16_t lds[16384];   // 32 KB: staging, then bounce
    bf16_t* lsA = lds;
    bf16_t* lsB = lds + 8192;

    const int tid  = threadIdx.x;
    const int lane = tid & 63;
    const int w    = tid >> 6;
    const int wm   = w & 1, wn = w >> 1;
    const int ll   = lane & 15;
    const int quad = lane >> 4;

    // xcd x owns m-panels [16x..16x+15]; inner = 4n x 3z per panel.
    const int bid   = blockIdx.x;
    const int x     = bid & 7;
    const int g     = bid >> 3;        // 0..191
    const int mi    = x * 16 + g / 12; // 0..127
    const int inner = g % 12;
    const int m0 = mi * 128;
    const int n0 = (inner & 3) * 128;
    const int z  = inner >> 2;         // 0..2

    const bf16_t* A = Xb;
    const bf16_t* B = Wb + z * 262144;

    f32x4 acc[4][4];
#pragma unroll
    for (int i = 0; i < 4; i++)
#pragma unroll
        for (int j = 0; j < 4; j++) acc[i][j] = (f32x4){0.f, 0.f, 0.f, 0.f};

    for (int k0 = 0; k0 < 512; k0 += 64) {
#pragma unroll
        for (int c = 0; c < 4; ++c) {
            const int base = (c * 4 + w) * 64;
            const int slot = base + lane;
            const int row  = slot >> 3;
            const int kc   = ((slot & 7) ^ (row & 7)) << 3;
            lds_dma16(A + (size_t)(m0 + row) * 512 + k0 + kc, (char*)lsA + base * 16);
            lds_dma16(B + (size_t)(n0 + row) * 512 + k0 + kc, (char*)lsB + base * 16);
        }
        __syncthreads();

#pragma unroll
        for (int t = 0; t < 2; t++) {
            short8 af[4], bf[4];
#pragma unroll
            for (int i = 0; i < 4; i++) {
                const int ri = wm * 64 + i * 16 + ll;
                const int rj = wn * 64 + i * 16 + ll;
                af[i] = *(const short8*)(lsA + ri * 64 + (((t * 4 + quad) ^ (ll & 7)) << 3));
                bf[i] = *(const short8*)(lsB + rj * 64 + (((t * 4 + quad) ^ (ll & 7)) << 3));
            }
#pragma unroll
            for (int i = 0; i < 4; i++)
#pragma unroll
                for (int j = 0; j < 4; j++)
                    acc[i][j] = __builtin_amdgcn_mfma_f32_16x16x32_bf16(af[i], bf[j], acc[i][j], 0, 0, 0);
        }
        __syncthreads();
    }

    // ---- epilogue: bounce through LDS for coalesced 16B stores ----
    bf16_t* wbuf = lds + w * 4096;     // 64x64 bf16 per wave
    const float inv = 0.044194173824159216f;  // 1/sqrt(512)

    if (z != 2) {
        const float* bptr = (z == 0) ? qb : kb;
        const float scl   = (z == 0) ? inv : 1.0f;
#pragma unroll
        for (int j = 0; j < 4; j++) {
            const int colL = j * 16 + ll;
            const float bv = bptr[n0 + wn * 64 + colL];
#pragma unroll
            for (int i = 0; i < 4; i++) {
                f32x4 a = acc[i][j];
#pragma unroll
                for (int r = 0; r < 4; r++) {
                    const int rowL = i * 16 + quad * 4 + r;
                    wbuf[rowL * 64 + (colL ^ ((rowL & 7) << 3))] = f2b((a[r] + bv) * scl);
                }
            }
        }
        __syncthreads();
        bf16_t* dst = (z == 0) ? Qb : Kb;
        const int rowg0 = m0 + wm * 64;
        const int colg0 = n0 + wn * 64;
#pragma unroll
        for (int k = 0; k < 8; k++) {
            const int rowL = (lane >> 3) + k * 8;
            const int c0   = (lane & 7) * 8;
            short8 vv = *(const short8*)(wbuf + rowL * 64 + (c0 ^ ((rowL & 7) << 3)));
            *(short8*)(dst + (size_t)(rowg0 + rowL) * 512 + colg0 + c0) = vv;
        }
    } else {
        // V: store transposed Vt[b][d][s]; bounce col-major (d-major)
#pragma unroll
        for (int j = 0; j < 4; j++) {
            const int d = j * 16 + ll;
            const float bv = vb[n0 + wn * 64 + d];
#pragma unroll
            for (int i = 0; i < 4; i++) {
                f32x4 a = acc[i][j];
                s4v pk;
                pk[0] = (short)f2b(a[0] + bv);
                pk[1] = (short)f2b(a[1] + bv);
                pk[2] = (short)f2b(a[2] + bv);
                pk[3] = (short)f2b(a[3] + bv);
                const int sB = i * 16 + quad * 4;
                *(s4v*)(wbuf + d * 64 + (sB ^ ((d & 7) << 3))) = pk;
            }
        }
        __syncthreads();
        const int rowg0 = m0 + wm * 64;
        const int b  = rowg0 >> 12;
        const int s0 = rowg0 & 4095;
        const int d0 = n0 + wn * 64;
#pragma unroll
        for (int k = 0; k < 8; k++) {
            const int dL = (lane >> 3) + k * 8;
            const int c0 = (lane & 7) * 8;
            short8 vv = *(const short8*)(wbuf + dL * 64 + (c0 ^ ((dL & 7) << 3)));
            *(short8*)(Vt + ((size_t)b * 512 + d0 + dL) * 4096 + s0 + c0) = vv;
        }
    }
}

// ---------- scores: P = sigmoid(Q K^T + bias) — ROUND-0 VERIFIED (157 us) ----------
// grid.x = 4096 flat: batch fastest (bias tile shared), then 4m x 8n supertiles.
__global__ __launch_bounds__(256)
void scores_sig(const bf16_t* __restrict__ Qb, const bf16_t* __restrict__ Kb,
                const float* __restrict__ bias, bf16_t* __restrict__ P)
{
    __shared__ bf16_t lsA[128 * 64];
    __shared__ bf16_t lsB[128 * 64];

    const int tid  = threadIdx.x;
    const int lane = tid & 63;
    const int w    = tid >> 6;
    const int wm   = w & 1, wn = w >> 1;
    const int ll   = lane & 15;
    const int quad = lane >> 4;

    const int bx  = blockIdx.x;
    const int z   = bx & 3;
    const int t_  = bx >> 2;              // 0..1023
    const int sup = t_ >> 5;              // 32 supertiles (8 in m x 4 in n)
    const int win = t_ & 31;              // 32 tiles per supertile (4m x 8n)
    const int m0  = ((sup >> 2) * 4 + (win & 3)) * 128;
    const int n0  = ((sup & 3) * 8 + (win >> 2)) * 128;

    const bf16_t* A = Qb + (size_t)z * 2097152;
    const bf16_t* B = Kb + (size_t)z * 2097152;
    bf16_t* out = P + (size_t)z * 16777216;

    f32x4 acc[4][4];
#pragma unroll
    for (int i = 0; i < 4; i++)
#pragma unroll
        for (int j = 0; j < 4; j++) acc[i][j] = (f32x4){0.f, 0.f, 0.f, 0.f};

    for (int k0 = 0; k0 < 512; k0 += 64) {
#pragma unroll
        for (int c = 0; c < 4; ++c) {
            const int base = (c * 4 + w) * 64;
            const int slot = base + lane;
            const int row  = slot >> 3;
            const int kc   = ((slot & 7) ^ (row & 7)) << 3;
            lds_dma16(A + (size_t)(m0 + row) * 512 + k0 + kc, (char*)lsA + base * 16);
            lds_dma16(B + (size_t)(n0 + row) * 512 + k0 + kc, (char*)lsB + base * 16);
        }
        __syncthreads();

#pragma unroll
        for (int t = 0; t < 2; t++) {
            short8 af[4], bf[4];
#pragma unroll
            for (int i = 0; i < 4; i++) {
                const int ri = wm * 64 + i * 16 + ll;
                const int rj = wn * 64 + i * 16 + ll;
                af[i] = *(const short8*)(lsA + ri * 64 + (((t * 4 + quad) ^ (ll & 7)) << 3));
                bf[i] = *(const short8*)(lsB + rj * 64 + (((t * 4 + quad) ^ (ll & 7)) << 3));
            }
#pragma unroll
            for (int i = 0; i < 4; i++)
#pragma unroll
                for (int j = 0; j < 4; j++)
                    acc[i][j] = __builtin_amdgcn_mfma_f32_16x16x32_bf16(af[i], bf[j], acc[i][j], 0, 0, 0);
        }
        __syncthreads();
    }

    // cheap sigmoid epilogue: fp32 bias (shared by 4 batch-siblings), truncated pack
#pragma unroll
    for (int i = 0; i < 4; i++) {
#pragma unroll
        for (int j = 0; j < 4; j++) {
            const int col  = n0 + wn * 64 + j * 16 + ll;
            const int rowb = m0 + wm * 64 + i * 16 + quad * 4;
            f32x4 a = acc[i][j];
#pragma unroll
            for (int r = 0; r < 4; r++) {
                const int row = rowb + r;
                const float v = a[r] + bias[(size_t)row * 4096 + col];
                const float p = __builtin_amdgcn_rcpf(1.f + __expf(-v));
                out[(size_t)row * 4096 + col] = (bf16_t)(__float_as_uint(p) >> 16);
            }
        }
    }
}

// ---------- PV: out = P * Vt^T, m97-style 128x128 tile, BK=64, K=4096 ----------
// Same verified tile structure as proj_all/scores_sig; K=4096 gives 64 K-steps
// (good barrier amortization).  grid (4, 32, 4) = 512 blocks, 32 KB LDS.
__global__ __launch_bounds__(256)
void pv_gemm(const bf16_t* __restrict__ P, const bf16_t* __restrict__ Vt,
             float* __restrict__ outg)
{
    __shared__ __align__(16) bf16_t lsA[128 * 64];   // 16 KB
    __shared__ __align__(16) bf16_t lsB[128 * 64];   // 16 KB

    const int tid  = threadIdx.x;
    const int lane = tid & 63;
    const int w    = tid >> 6;
    const int wm   = w & 1, wn = w >> 1;
    const int ll   = lane & 15;
    const int quad = lane >> 4;

    const int n0 = blockIdx.x * 128;   // 0..511 (d dimension)
    const int m0 = blockIdx.y * 128;   // 0..4095 (q dimension)
    const int z  = blockIdx.z;

    const bf16_t* A = P + (size_t)z * 16777216;   // [4096][4096]
    const bf16_t* B = Vt + (size_t)z * 2097152;   // [512][4096]
    float* out = outg + (size_t)z * 2097152;

    f32x4 acc[4][4];
#pragma unroll
    for (int i = 0; i < 4; i++)
#pragma unroll
        for (int j = 0; j < 4; j++) acc[i][j] = (f32x4){0.f, 0.f, 0.f, 0.f};

    for (int k0 = 0; k0 < 4096; k0 += 64) {
#pragma unroll
        for (int c = 0; c < 4; ++c) {
            const int base = (c * 4 + w) * 64;
            const int slot = base + lane;
            const int row  = slot >> 3;
            const int kc   = ((slot & 7) ^ (row & 7)) << 3;
            lds_dma16(A + (size_t)(m0 + row) * 4096 + k0 + kc, (char*)lsA + base * 16);
            lds_dma16(B + (size_t)(n0 + row) * 4096 + k0 + kc, (char*)lsB + base * 16);
        }
        __syncthreads();

#pragma unroll
        for (int t = 0; t < 2; t++) {
            short8 af[4], bf[4];
#pragma unroll
            for (int i = 0; i < 4; i++) {
                const int ri = wm * 64 + i * 16 + ll;
                const int rj = wn * 64 + i * 16 + ll;
                af[i] = *(const short8*)(lsA + ri * 64 + (((t * 4 + quad) ^ (ll & 7)) << 3));
                bf[i] = *(const short8*)(lsB + rj * 64 + (((t * 4 + quad) ^ (ll & 7)) << 3));
            }
#pragma unroll
            for (int i = 0; i < 4; i++)
#pragma unroll
                for (int j = 0; j < 4; j++)
                    acc[i][j] = __builtin_amdgcn_mfma_f32_16x16x32_bf16(af[i], bf[j], acc[i][j], 0, 0, 0);
        }
        __syncthreads();
    }

#pragma unroll
    for (int i = 0; i < 4; i++) {
#pragma unroll
        for (int j = 0; j < 4; j++) {
            const int col  = n0 + wn * 64 + j * 16 + ll;
            const int rowb = m0 + wm * 64 + i * 16 + quad * 4;
            f32x4 a = acc[i][j];
#pragma unroll
            for (int r = 0; r < 4; r++)
                out[(size_t)(rowb + r) * 512 + col] = a[r];
        }
    }
}

extern "C" void kernel_launch(void* const* d_in, const int* in_sizes, int n_in,
                              void* d_out, int out_size, void* d_ws, size_t ws_size,
                              hipStream_t stream) {
    (void)in_sizes; (void)n_in; (void)out_size; (void)ws_size;
    const float* x    = (const float*)d_in[0];
    const float* bias = (const float*)d_in[1];
    const float* Wq_w = (const float*)d_in[2];
    const float* Wq_b = (const float*)d_in[3];
    const float* Wk_w = (const float*)d_in[4];
    const float* Wk_b = (const float*)d_in[5];
    const float* Wv_w = (const float*)d_in[6];
    const float* Wv_b = (const float*)d_in[7];
    float* out = (float*)d_out;

    // workspace layout (bf16 elements)
    bf16_t* Xb = (bf16_t*)d_ws;                    // 16384 x 512
    bf16_t* Wb = Xb + (size_t)16384 * 512;         // 3 x 512 x 512
    bf16_t* Qb = Wb + (size_t)3 * 512 * 512;       // 16384 x 512 (pre-scaled 1/sqrt(D))
    bf16_t* Kb = Qb + (size_t)16384 * 512;         // 16384 x 512
    bf16_t* Vt = Kb + (size_t)16384 * 512;         // 4 x 512 x 4096 (transposed V)
    bf16_t* P  = Vt + (size_t)16384 * 512;         // 4 x 4096 x 4096

    cvt_f32_bf16<<<8192, 256, 0, stream>>>(x, Xb, 2097152);
    cvt_w3<<<768, 256, 0, stream>>>(Wq_w, Wk_w, Wv_w, Wb);

    // all three projections in one launch
    proj_all<<<1536, 256, 0, stream>>>(Xb, Wb, Wq_b, Wk_b, Wv_b, Qb, Kb, Vt);
    // scores + sigmoid (round-0 verified config)
    scores_sig<<<4096, 256, 0, stream>>>(Qb, Kb, bias, P);
    // out = P * V, 128x128 m97-style tiles, BK=64
    pv_gemm<<<dim3(4, 32, 4), 256, 0, stream>>>(P, Vt, out);
}

// Round 6
// 386.481 us; speedup vs baseline: 1.4119x; 1.0676x over previous
//
#include <hip/hip_runtime.h>
#include <hip/hip_bf16.h>
#include <stdint.h>

typedef unsigned short bf16_t;
typedef __attribute__((ext_vector_type(4))) short s4v;
typedef __attribute__((ext_vector_type(8))) short short8;
typedef __attribute__((ext_vector_type(4))) float f32x4;

__device__ __forceinline__ bf16_t f2b(float f) {
    union { float f; uint32_t u; } v; v.f = f;
    uint32_t u = v.u;
    return (bf16_t)((u + 0x7FFFu + ((u >> 16) & 1u)) >> 16);
}

__global__ __launch_bounds__(256) void cvt_f32_bf16(const float* __restrict__ in,
                                                    bf16_t* __restrict__ out, int n4) {
    int i = blockIdx.x * blockDim.x + threadIdx.x;
    if (i >= n4) return;
    float4 f = ((const float4*)in)[i];
    ushort4 o;
    o.x = f2b(f.x); o.y = f2b(f.y); o.z = f2b(f.z); o.w = f2b(f.w);
    ((ushort4*)out)[i] = o;
}

// three 512x512 weight matrices in one launch
__global__ __launch_bounds__(256) void cvt_w3(const float* __restrict__ a,
                                              const float* __restrict__ b,
                                              const float* __restrict__ c,
                                              bf16_t* __restrict__ out) {
    int i = blockIdx.x * blockDim.x + threadIdx.x;   // 0..196607
    const int which = i >> 16;
    const int idx   = i & 65535;
    const float* src = (which == 0) ? a : (which == 1) ? b : c;
    float4 f = ((const float4*)src)[idx];
    ushort4 o;
    o.x = f2b(f.x); o.y = f2b(f.y); o.z = f2b(f.z); o.w = f2b(f.w);
    ((ushort4*)out)[i] = o;
}

__device__ __forceinline__ void lds_dma16(const void* g, void* l) {
    __builtin_amdgcn_global_load_lds(
        (const __attribute__((address_space(1))) void*)g,
        (__attribute__((address_space(3))) void*)l, 16, 0, 0);
}

// BK=64 swizzle contract: LDS[row][ch] holds global chunk (ch ^ (row&7));
// reader wanting global chunk g of row r reads LDS[r][g ^ (r&7)].
// 2-phase loop contract (T3 minimum recipe):
//   prologue: STAGE(buf0, kt=0); barrier.
//   iter kt:  STAGE(buf[cur^1], kt+1)  [targets buffer NOT read this iter]
//             ds_read+MFMA from buf[cur]; __syncthreads() [drains vmcnt +
//             protects WAR across waves]; cur ^= 1.
//   One barrier per K-step (was two); stage latency hides under MFMA.

// ---------- projections: Q/K/V fused, flat grid (1536 blocks) ----------
__global__ __launch_bounds__(256)
void proj_all(const bf16_t* __restrict__ Xb, const bf16_t* __restrict__ Wb,
              const float* __restrict__ qb, const float* __restrict__ kb,
              const float* __restrict__ vb,
              bf16_t* __restrict__ Qb, bf16_t* __restrict__ Kb,
              bf16_t* __restrict__ Vt)
{
    __shared__ __align__(16) bf16_t lds[2][16384];   // 64 KB: 2 x (A 16KB | B 16KB)

    const int tid  = threadIdx.x;
    const int lane = tid & 63;
    const int w    = tid >> 6;
    const int wm   = w & 1, wn = w >> 1;
    const int ll   = lane & 15;
    const int quad = lane >> 4;

    // xcd x owns m-panels [16x..16x+15]; inner = 4n x 3z per panel.
    const int bid   = blockIdx.x;
    const int x     = bid & 7;
    const int g     = bid >> 3;        // 0..191
    const int mi    = x * 16 + g / 12; // 0..127
    const int inner = g % 12;
    const int m0 = mi * 128;
    const int n0 = (inner & 3) * 128;
    const int z  = inner >> 2;         // 0..2

    const bf16_t* A = Xb;
    const bf16_t* B = Wb + z * 262144;

    auto stage = [&](int kt, int b) {
#pragma unroll
        for (int c = 0; c < 4; ++c) {
            const int base = (c * 4 + w) * 64;
            const int slot = base + lane;
            const int row  = slot >> 3;
            const int kc   = ((slot & 7) ^ (row & 7)) << 3;
            lds_dma16(A + (size_t)(m0 + row) * 512 + kt * 64 + kc, (char*)&lds[b][0]    + base * 16);
            lds_dma16(B + (size_t)(n0 + row) * 512 + kt * 64 + kc, (char*)&lds[b][8192] + base * 16);
        }
    };

    f32x4 acc[4][4];
#pragma unroll
    for (int i = 0; i < 4; i++)
#pragma unroll
        for (int j = 0; j < 4; j++) acc[i][j] = (f32x4){0.f, 0.f, 0.f, 0.f};

    stage(0, 0);
    __syncthreads();
    int cur = 0;
    for (int kt = 0; kt < 8; ++kt) {
        if (kt < 7) stage(kt + 1, cur ^ 1);
        const bf16_t* lsA = &lds[cur][0];
        const bf16_t* lsB = &lds[cur][8192];
#pragma unroll
        for (int t = 0; t < 2; t++) {
            short8 af[4], bf[4];
#pragma unroll
            for (int i = 0; i < 4; i++) {
                const int ri = wm * 64 + i * 16 + ll;
                const int rj = wn * 64 + i * 16 + ll;
                af[i] = *(const short8*)(lsA + ri * 64 + (((t * 4 + quad) ^ (ll & 7)) << 3));
                bf[i] = *(const short8*)(lsB + rj * 64 + (((t * 4 + quad) ^ (ll & 7)) << 3));
            }
#pragma unroll
            for (int i = 0; i < 4; i++)
#pragma unroll
                for (int j = 0; j < 4; j++)
                    acc[i][j] = __builtin_amdgcn_mfma_f32_16x16x32_bf16(af[i], bf[j], acc[i][j], 0, 0, 0);
        }
        __syncthreads();
        cur ^= 1;
    }

    // ---- epilogue: bounce through LDS for coalesced 16B stores ----
    bf16_t* wbuf = &lds[0][0] + w * 4096;     // 64x64 bf16 per wave (32 KB in buf0)
    const float inv = 0.044194173824159216f;  // 1/sqrt(512)

    if (z != 2) {
        const float* bptr = (z == 0) ? qb : kb;
        const float scl   = (z == 0) ? inv : 1.0f;
#pragma unroll
        for (int j = 0; j < 4; j++) {
            const int colL = j * 16 + ll;
            const float bv = bptr[n0 + wn * 64 + colL];
#pragma unroll
            for (int i = 0; i < 4; i++) {
                f32x4 a = acc[i][j];
#pragma unroll
                for (int r = 0; r < 4; r++) {
                    const int rowL = i * 16 + quad * 4 + r;
                    wbuf[rowL * 64 + (colL ^ ((rowL & 7) << 3))] = f2b((a[r] + bv) * scl);
                }
            }
        }
        __syncthreads();
        bf16_t* dst = (z == 0) ? Qb : Kb;
        const int rowg0 = m0 + wm * 64;
        const int colg0 = n0 + wn * 64;
#pragma unroll
        for (int k = 0; k < 8; k++) {
            const int rowL = (lane >> 3) + k * 8;
            const int c0   = (lane & 7) * 8;
            short8 vv = *(const short8*)(wbuf + rowL * 64 + (c0 ^ ((rowL & 7) << 3)));
            *(short8*)(dst + (size_t)(rowg0 + rowL) * 512 + colg0 + c0) = vv;
        }
    } else {
        // V: store transposed Vt[b][d][s]; bounce col-major (d-major)
#pragma unroll
        for (int j = 0; j < 4; j++) {
            const int d = j * 16 + ll;
            const float bv = vb[n0 + wn * 64 + d];
#pragma unroll
            for (int i = 0; i < 4; i++) {
                f32x4 a = acc[i][j];
                s4v pk;
                pk[0] = (short)f2b(a[0] + bv);
                pk[1] = (short)f2b(a[1] + bv);
                pk[2] = (short)f2b(a[2] + bv);
                pk[3] = (short)f2b(a[3] + bv);
                const int sB = i * 16 + quad * 4;
                *(s4v*)(wbuf + d * 64 + (sB ^ ((d & 7) << 3))) = pk;
            }
        }
        __syncthreads();
        const int rowg0 = m0 + wm * 64;
        const int b  = rowg0 >> 12;
        const int s0 = rowg0 & 4095;
        const int d0 = n0 + wn * 64;
#pragma unroll
        for (int k = 0; k < 8; k++) {
            const int dL = (lane >> 3) + k * 8;
            const int c0 = (lane & 7) * 8;
            short8 vv = *(const short8*)(wbuf + dL * 64 + (c0 ^ ((dL & 7) << 3)));
            *(short8*)(Vt + ((size_t)b * 512 + d0 + dL) * 4096 + s0 + c0) = vv;
        }
    }
}

// ---------- scores: P = sigmoid(Q K^T + bias), 2-phase dbuf ----------
// grid.x = 4096 flat: batch fastest (bias tile shared), then 4m x 8n supertiles.
__global__ __launch_bounds__(256)
void scores_sig(const bf16_t* __restrict__ Qb, const bf16_t* __restrict__ Kb,
                const float* __restrict__ bias, bf16_t* __restrict__ P)
{
    __shared__ __align__(16) bf16_t lds[2][16384];   // 64 KB

    const int tid  = threadIdx.x;
    const int lane = tid & 63;
    const int w    = tid >> 6;
    const int wm   = w & 1, wn = w >> 1;
    const int ll   = lane & 15;
    const int quad = lane >> 4;

    const int bx  = blockIdx.x;
    const int z   = bx & 3;
    const int t_  = bx >> 2;              // 0..1023
    const int sup = t_ >> 5;              // 32 supertiles (8 in m x 4 in n)
    const int win = t_ & 31;              // 32 tiles per supertile (4m x 8n)
    const int m0  = ((sup >> 2) * 4 + (win & 3)) * 128;
    const int n0  = ((sup & 3) * 8 + (win >> 2)) * 128;

    const bf16_t* A = Qb + (size_t)z * 2097152;
    const bf16_t* B = Kb + (size_t)z * 2097152;
    bf16_t* out = P + (size_t)z * 16777216;

    auto stage = [&](int kt, int b) {
#pragma unroll
        for (int c = 0; c < 4; ++c) {
            const int base = (c * 4 + w) * 64;
            const int slot = base + lane;
            const int row  = slot >> 3;
            const int kc   = ((slot & 7) ^ (row & 7)) << 3;
            lds_dma16(A + (size_t)(m0 + row) * 512 + kt * 64 + kc, (char*)&lds[b][0]    + base * 16);
            lds_dma16(B + (size_t)(n0 + row) * 512 + kt * 64 + kc, (char*)&lds[b][8192] + base * 16);
        }
    };

    f32x4 acc[4][4];
#pragma unroll
    for (int i = 0; i < 4; i++)
#pragma unroll
        for (int j = 0; j < 4; j++) acc[i][j] = (f32x4){0.f, 0.f, 0.f, 0.f};

    stage(0, 0);
    __syncthreads();
    int cur = 0;
    for (int kt = 0; kt < 8; ++kt) {
        if (kt < 7) stage(kt + 1, cur ^ 1);
        const bf16_t* lsA = &lds[cur][0];
        const bf16_t* lsB = &lds[cur][8192];
#pragma unroll
        for (int t = 0; t < 2; t++) {
            short8 af[4], bf[4];
#pragma unroll
            for (int i = 0; i < 4; i++) {
                const int ri = wm * 64 + i * 16 + ll;
                const int rj = wn * 64 + i * 16 + ll;
                af[i] = *(const short8*)(lsA + ri * 64 + (((t * 4 + quad) ^ (ll & 7)) << 3));
                bf[i] = *(const short8*)(lsB + rj * 64 + (((t * 4 + quad) ^ (ll & 7)) << 3));
            }
#pragma unroll
            for (int i = 0; i < 4; i++)
#pragma unroll
                for (int j = 0; j < 4; j++)
                    acc[i][j] = __builtin_amdgcn_mfma_f32_16x16x32_bf16(af[i], bf[j], acc[i][j], 0, 0, 0);
        }
        __syncthreads();
        cur ^= 1;
    }

    // cheap sigmoid epilogue: fp32 bias (shared by 4 batch-siblings), truncated pack
#pragma unroll
    for (int i = 0; i < 4; i++) {
#pragma unroll
        for (int j = 0; j < 4; j++) {
            const int col  = n0 + wn * 64 + j * 16 + ll;
            const int rowb = m0 + wm * 64 + i * 16 + quad * 4;
            f32x4 a = acc[i][j];
#pragma unroll
            for (int r = 0; r < 4; r++) {
                const int row = rowb + r;
                const float v = a[r] + bias[(size_t)row * 4096 + col];
                const float p = __builtin_amdgcn_rcpf(1.f + __expf(-v));
                out[(size_t)row * 4096 + col] = (bf16_t)(__float_as_uint(p) >> 16);
            }
        }
    }
}

// ---------- PV: out = P * Vt^T, 128x128 tile, BK=64, K=4096, 2-phase dbuf ----------
__global__ __launch_bounds__(256)
void pv_gemm(const bf16_t* __restrict__ P, const bf16_t* __restrict__ Vt,
             float* __restrict__ outg)
{
    __shared__ __align__(16) bf16_t lds[2][16384];   // 64 KB

    const int tid  = threadIdx.x;
    const int lane = tid & 63;
    const int w    = tid >> 6;
    const int wm   = w & 1, wn = w >> 1;
    const int ll   = lane & 15;
    const int quad = lane >> 4;

    const int n0 = blockIdx.x * 128;   // 0..511 (d dimension)
    const int m0 = blockIdx.y * 128;   // 0..4095 (q dimension)
    const int z  = blockIdx.z;

    const bf16_t* A = P + (size_t)z * 16777216;   // [4096][4096]
    const bf16_t* B = Vt + (size_t)z * 2097152;   // [512][4096]
    float* out = outg + (size_t)z * 2097152;

    auto stage = [&](int kt, int b) {
#pragma unroll
        for (int c = 0; c < 4; ++c) {
            const int base = (c * 4 + w) * 64;
            const int slot = base + lane;
            const int row  = slot >> 3;
            const int kc   = ((slot & 7) ^ (row & 7)) << 3;
            lds_dma16(A + (size_t)(m0 + row) * 4096 + kt * 64 + kc, (char*)&lds[b][0]    + base * 16);
            lds_dma16(B + (size_t)(n0 + row) * 4096 + kt * 64 + kc, (char*)&lds[b][8192] + base * 16);
        }
    };

    f32x4 acc[4][4];
#pragma unroll
    for (int i = 0; i < 4; i++)
#pragma unroll
        for (int j = 0; j < 4; j++) acc[i][j] = (f32x4){0.f, 0.f, 0.f, 0.f};

    stage(0, 0);
    __syncthreads();
    int cur = 0;
    for (int kt = 0; kt < 64; ++kt) {
        if (kt < 63) stage(kt + 1, cur ^ 1);
        const bf16_t* lsA = &lds[cur][0];
        const bf16_t* lsB = &lds[cur][8192];
#pragma unroll
        for (int t = 0; t < 2; t++) {
            short8 af[4], bf[4];
#pragma unroll
            for (int i = 0; i < 4; i++) {
                const int ri = wm * 64 + i * 16 + ll;
                const int rj = wn * 64 + i * 16 + ll;
                af[i] = *(const short8*)(lsA + ri * 64 + (((t * 4 + quad) ^ (ll & 7)) << 3));
                bf[i] = *(const short8*)(lsB + rj * 64 + (((t * 4 + quad) ^ (ll & 7)) << 3));
            }
#pragma unroll
            for (int i = 0; i < 4; i++)
#pragma unroll
                for (int j = 0; j < 4; j++)
                    acc[i][j] = __builtin_amdgcn_mfma_f32_16x16x32_bf16(af[i], bf[j], acc[i][j], 0, 0, 0);
        }
        __syncthreads();
        cur ^= 1;
    }

#pragma unroll
    for (int i = 0; i < 4; i++) {
#pragma unroll
        for (int j = 0; j < 4; j++) {
            const int col  = n0 + wn * 64 + j * 16 + ll;
            const int rowb = m0 + wm * 64 + i * 16 + quad * 4;
            f32x4 a = acc[i][j];
#pragma unroll
            for (int r = 0; r < 4; r++)
                out[(size_t)(rowb + r) * 512 + col] = a[r];
        }
    }
}

extern "C" void kernel_launch(void* const* d_in, const int* in_sizes, int n_in,
                              void* d_out, int out_size, void* d_ws, size_t ws_size,
                              hipStream_t stream) {
    (void)in_sizes; (void)n_in; (void)out_size; (void)ws_size;
    const float* x    = (const float*)d_in[0];
    const float* bias = (const float*)d_in[1];
    const float* Wq_w = (const float*)d_in[2];
    const float* Wq_b = (const float*)d_in[3];
    const float* Wk_w = (const float*)d_in[4];
    const float* Wk_b = (const float*)d_in[5];
    const float* Wv_w = (const float*)d_in[6];
    const float* Wv_b = (const float*)d_in[7];
    float* out = (float*)d_out;

    // workspace layout (bf16 elements)
    bf16_t* Xb = (bf16_t*)d_ws;                    // 16384 x 512
    bf16_t* Wb = Xb + (size_t)16384 * 512;         // 3 x 512 x 512
    bf16_t* Qb = Wb + (size_t)3 * 512 * 512;       // 16384 x 512 (pre-scaled 1/sqrt(D))
    bf16_t* Kb = Qb + (size_t)16384 * 512;         // 16384 x 512
    bf16_t* Vt = Kb + (size_t)16384 * 512;         // 4 x 512 x 4096 (transposed V)
    bf16_t* P  = Vt + (size_t)16384 * 512;         // 4 x 4096 x 4096

    cvt_f32_bf16<<<8192, 256, 0, stream>>>(x, Xb, 2097152);
    cvt_w3<<<768, 256, 0, stream>>>(Wq_w, Wk_w, Wv_w, Wb);

    // all three projections in one launch
    proj_all<<<1536, 256, 0, stream>>>(Xb, Wb, Wq_b, Wk_b, Wv_b, Qb, Kb, Vt);
    // scores + sigmoid (2-phase dbuf)
    scores_sig<<<4096, 256, 0, stream>>>(Qb, Kb, bias, P);
    // out = P * V, 128x128 tiles, BK=64, 2-phase dbuf
    pv_gemm<<<dim3(4, 32, 4), 256, 0, stream>>>(P, Vt, out);
}